// Round 1
// baseline (576.984 us; speedup 1.0000x reference)
//
#include <hip/hip_runtime.h>
#include <hip/hip_bf16.h>
#include <cstdint>
#include <cstddef>

#define DEVINL __device__ __forceinline__

typedef __attribute__((ext_vector_type(4))) float f32x4;
typedef __attribute__((ext_vector_type(8))) short s16x8;

// round-to-nearest-even f32 -> bf16 bits
DEVINL short f2bf(float f) {
  union { float f; unsigned u; } v; v.f = f;
  unsigned r = (v.u + 0x7fffu + ((v.u >> 16) & 1u)) >> 16;
  return (short)r;
}

DEVINL void gload_lds16(const void* g, void* l) {
  __builtin_amdgcn_global_load_lds((const __attribute__((address_space(1))) void*)g,
                                   (__attribute__((address_space(3))) void*)l,
                                   16, 0, 0);
}

// ---------------------------------------------------------------------------
// GEMM: C(M,N) = A(M,K) @ Bt(N,K)^T, bf16 inputs, f32 accum, fused epilogues.
// 128x128 tile, BK=32, 4 waves (2x2), each wave 64x64 (4x4 frags of 16x16).
// ---------------------------------------------------------------------------
enum { EPI_F32 = 0, EPI_GELU = 1, EPI_RES = 2, EPI_QKV = 3 };

template <int EPI>
__global__ __launch_bounds__(256) void gemm_bt(
    const short* __restrict__ A, const short* __restrict__ Bt,
    const float* __restrict__ bias, const float* __restrict__ res,
    float* __restrict__ outF, short* __restrict__ outB,
    short* __restrict__ qp, short* __restrict__ kp, short* __restrict__ vp,
    int M, int N, int K)
{
  __shared__ short As[128 * 32];
  __shared__ short Bs[128 * 32];
  const int tid = threadIdx.x;
  const int w = tid >> 6, lane = tid & 63;
  const int wr = w >> 1, wc = w & 1;
  const int n0 = blockIdx.x * 128, m0 = blockIdx.y * 128;
  const int lrow = lane >> 2, lk = (lane & 3) << 3;

  const short* Ag = A + (size_t)m0 * K;
  const short* Bg = Bt + (size_t)n0 * K;

  f32x4 acc[4][4] = {};

  for (int kk = 0; kk < K; kk += 32) {
#pragma unroll
    for (int i = 0; i < 2; ++i) {
      const int c = w * 2 + i;  // chunk 0..7: rows c*16..c*16+15 of the tile
      gload_lds16(Ag + (size_t)(c * 16 + lrow) * K + (kk + lk), &As[c * 512]);
      gload_lds16(Bg + (size_t)(c * 16 + lrow) * K + (kk + lk), &Bs[c * 512]);
    }
    __syncthreads();
    s16x8 af[4], bf[4];
#pragma unroll
    for (int mi = 0; mi < 4; ++mi)
      af[mi] = *(const s16x8*)&As[(wr * 64 + mi * 16 + (lane & 15)) * 32 + ((lane >> 4) << 3)];
#pragma unroll
    for (int ni = 0; ni < 4; ++ni)
      bf[ni] = *(const s16x8*)&Bs[(wc * 64 + ni * 16 + (lane & 15)) * 32 + ((lane >> 4) << 3)];
#pragma unroll
    for (int mi = 0; mi < 4; ++mi)
#pragma unroll
      for (int ni = 0; ni < 4; ++ni)
        acc[mi][ni] = __builtin_amdgcn_mfma_f32_16x16x32_bf16(af[mi], bf[ni], acc[mi][ni], 0, 0, 0);
    __syncthreads();
  }

  // epilogue: D row = m0+wr*64+mi*16+(lane>>4)*4+j, col = n0+wc*64+ni*16+(lane&15)
  const int rbase = m0 + wr * 64 + ((lane >> 4) << 2);
  const int cbase = n0 + wc * 64 + (lane & 15);
#pragma unroll
  for (int mi = 0; mi < 4; ++mi) {
#pragma unroll
    for (int ni = 0; ni < 4; ++ni) {
      const int col = cbase + ni * 16;
      const float bv = bias[col];
#pragma unroll
      for (int j = 0; j < 4; ++j) {
        const int row = rbase + mi * 16 + j;
        float v = acc[mi][ni][j] + bv;
        if (EPI == EPI_QKV) {
          const int id = col >> 10, e = col & 1023;
          const int h = e >> 6, d = e & 63;
          const int b = row >> 11, t = row & 2047;
          const size_t o = ((size_t)(b * 16 + h) * 2048 + t) * 64 + d;
          if (id == 0)      qp[o] = f2bf(v * 0.125f);   // fold 1/sqrt(64) into q
          else if (id == 1) kp[o] = f2bf(v);
          else              vp[o] = f2bf(v);
        } else if (EPI == EPI_GELU) {
          outB[(size_t)row * N + col] = f2bf(0.5f * v * (1.0f + erff(v * 0.70710678118654752f)));
        } else if (EPI == EPI_RES) {
          outF[(size_t)row * N + col] = v + res[(size_t)row * N + col];
        } else {
          outF[(size_t)row * N + col] = v;
        }
      }
    }
  }
}

// ---------------------------------------------------------------------------
// Flash attention, no mask. Grid: (B*H=32, T/128=16). 4 waves x 32 q-rows.
// q,k,v head-major (bh, t, 64) bf16; q pre-scaled by 1/8. Out: (B,T,E) bf16.
// ---------------------------------------------------------------------------
__global__ __launch_bounds__(256) void attn_kernel(
    const short* __restrict__ qg, const short* __restrict__ kg,
    const short* __restrict__ vg, short* __restrict__ outB)
{
  __shared__ short Ks[64 * 72];     // [s][d], pad 72 to break bank conflicts
  __shared__ short Vs[64 * 72];     // [d][s] (transposed at stage time)
  __shared__ short Ps[4][32 * 72];  // per-wave P tile [q][s]

  const int bh = blockIdx.x, qb = blockIdx.y;
  const int tid = threadIdx.x, w = tid >> 6, lane = tid & 63;
  const int b = bh >> 4, h = bh & 15;
  const int qr0 = qb * 128 + w * 32;

  s16x8 qf[2][2];
#pragma unroll
  for (int mi = 0; mi < 2; ++mi)
#pragma unroll
    for (int kk = 0; kk < 2; ++kk)
      qf[mi][kk] = *(const s16x8*)&qg[((size_t)bh * 2048 + qr0 + mi * 16 + (lane & 15)) * 64
                                      + kk * 32 + ((lane >> 4) << 3)];

  f32x4 o[2][4] = {};
  float mrow[2][4], lrow[2][4];
#pragma unroll
  for (int mi = 0; mi < 2; ++mi)
#pragma unroll
    for (int j = 0; j < 4; ++j) { mrow[mi][j] = -1e30f; lrow[mi][j] = 0.f; }

  for (int s0 = 0; s0 < 2048; s0 += 64) {
#pragma unroll
    for (int it = 0; it < 2; ++it) {
      const int r = it * 32 + (tid >> 3), g = tid & 7;
      const size_t src = ((size_t)bh * 2048 + s0 + r) * 64 + g * 8;
      s16x8 kv = *(const s16x8*)&kg[src];
      *(s16x8*)&Ks[r * 72 + g * 8] = kv;
      s16x8 vv = *(const s16x8*)&vg[src];
#pragma unroll
      for (int e = 0; e < 8; ++e) Vs[(g * 8 + e) * 72 + r] = vv[e];
    }
    __syncthreads();

    // S = Q K^T (q pre-scaled)
    f32x4 sc[2][4] = {};
    s16x8 kf[4][2];
#pragma unroll
    for (int ni = 0; ni < 4; ++ni)
#pragma unroll
      for (int kk = 0; kk < 2; ++kk)
        kf[ni][kk] = *(const s16x8*)&Ks[(ni * 16 + (lane & 15)) * 72 + kk * 32 + ((lane >> 4) << 3)];
#pragma unroll
    for (int mi = 0; mi < 2; ++mi)
#pragma unroll
      for (int ni = 0; ni < 4; ++ni)
#pragma unroll
        for (int kk = 0; kk < 2; ++kk)
          sc[mi][ni] = __builtin_amdgcn_mfma_f32_16x16x32_bf16(qf[mi][kk], kf[ni][kk], sc[mi][ni], 0, 0, 0);

    // online softmax: rows spread over 16-lane groups (D layout), reduce via shfl_xor
#pragma unroll
    for (int mi = 0; mi < 2; ++mi) {
#pragma unroll
      for (int j = 0; j < 4; ++j) {
        float pm = fmaxf(fmaxf(sc[mi][0][j], sc[mi][1][j]), fmaxf(sc[mi][2][j], sc[mi][3][j]));
#pragma unroll
        for (int msk = 1; msk < 16; msk <<= 1) pm = fmaxf(pm, __shfl_xor(pm, msk));
        const float mn = fmaxf(mrow[mi][j], pm);
        const float alpha = __expf(mrow[mi][j] - mn);
        mrow[mi][j] = mn;
        float rs = 0.f;
#pragma unroll
        for (int ni = 0; ni < 4; ++ni) {
          const float p = __expf(sc[mi][ni][j] - mn);
          sc[mi][ni][j] = p;
          rs += p;
          o[mi][ni][j] *= alpha;
        }
#pragma unroll
        for (int msk = 1; msk < 16; msk <<= 1) rs += __shfl_xor(rs, msk);
        lrow[mi][j] = lrow[mi][j] * alpha + rs;
      }
    }

    // P -> per-wave LDS (D layout -> A layout re-read)
#pragma unroll
    for (int mi = 0; mi < 2; ++mi)
#pragma unroll
      for (int ni = 0; ni < 4; ++ni)
#pragma unroll
        for (int j = 0; j < 4; ++j)
          Ps[w][(mi * 16 + ((lane >> 4) << 2) + j) * 72 + ni * 16 + (lane & 15)] = f2bf(sc[mi][ni][j]);

    s16x8 vf[4][2], pf[2][2];
#pragma unroll
    for (int ni = 0; ni < 4; ++ni)
#pragma unroll
      for (int kk = 0; kk < 2; ++kk)
        vf[ni][kk] = *(const s16x8*)&Vs[(ni * 16 + (lane & 15)) * 72 + kk * 32 + ((lane >> 4) << 3)];
#pragma unroll
    for (int mi = 0; mi < 2; ++mi)
#pragma unroll
      for (int kk = 0; kk < 2; ++kk)
        pf[mi][kk] = *(const s16x8*)&Ps[w][(mi * 16 + (lane & 15)) * 72 + kk * 32 + ((lane >> 4) << 3)];
#pragma unroll
    for (int mi = 0; mi < 2; ++mi)
#pragma unroll
      for (int ni = 0; ni < 4; ++ni)
#pragma unroll
        for (int kk = 0; kk < 2; ++kk)
          o[mi][ni] = __builtin_amdgcn_mfma_f32_16x16x32_bf16(pf[mi][kk], vf[ni][kk], o[mi][ni], 0, 0, 0);
    __syncthreads();
  }

#pragma unroll
  for (int mi = 0; mi < 2; ++mi) {
#pragma unroll
    for (int j = 0; j < 4; ++j) {
      const float inv = 1.f / lrow[mi][j];
      const int t = qr0 + mi * 16 + ((lane >> 4) << 2) + j;
#pragma unroll
      for (int ni = 0; ni < 4; ++ni) {
        const int d = ni * 16 + (lane & 15);
        outB[((size_t)(b * 2048 + t)) * 1024 + h * 64 + d] = f2bf(o[mi][ni][j] * inv);
      }
    }
  }
}

// ---------------------------------------------------------------------------
// LayerNorm over C=1024, one row per block, in-place f32 + bf16 copy.
// ---------------------------------------------------------------------------
__global__ __launch_bounds__(256) void ln_kernel(
    const float* in, float* outF, short* __restrict__ outB,
    const float* __restrict__ gw, const float* __restrict__ bw)
{
  const int row = blockIdx.x, tid = threadIdx.x;
  const float4 v = ((const float4*)(in + (size_t)row * 1024))[tid];
  float s = v.x + v.y + v.z + v.w;
  float s2 = v.x * v.x + v.y * v.y + v.z * v.z + v.w * v.w;
#pragma unroll
  for (int m = 1; m < 64; m <<= 1) { s += __shfl_xor(s, m); s2 += __shfl_xor(s2, m); }
  __shared__ float as1[4], as2[4];
  if ((tid & 63) == 0) { as1[tid >> 6] = s; as2[tid >> 6] = s2; }
  __syncthreads();
  s = as1[0] + as1[1] + as1[2] + as1[3];
  s2 = as2[0] + as2[1] + as2[2] + as2[3];
  const float mu = s * (1.f / 1024.f);
  const float var = s2 * (1.f / 1024.f) - mu * mu;
  const float rstd = rsqrtf(var + 1e-5f);
  const float4 g = ((const float4*)gw)[tid];
  const float4 bb = ((const float4*)bw)[tid];
  float4 y;
  y.x = (v.x - mu) * rstd * g.x + bb.x;
  y.y = (v.y - mu) * rstd * g.y + bb.y;
  y.z = (v.z - mu) * rstd * g.z + bb.z;
  y.w = (v.w - mu) * rstd * g.w + bb.w;
  ((float4*)(outF + (size_t)row * 1024))[tid] = y;
  short4 ob; ob.x = f2bf(y.x); ob.y = f2bf(y.y); ob.z = f2bf(y.z); ob.w = f2bf(y.w);
  ((short4*)(outB + (size_t)row * 1024))[tid] = ob;
}

// src (R,Cc) f32 -> dst (Cc,R) bf16
__global__ __launch_bounds__(256) void transpose_cast(
    const float* __restrict__ src, short* __restrict__ dst, int R, int Cc)
{
  __shared__ float tile[32][33];
  const int c0 = blockIdx.x * 32, r0 = blockIdx.y * 32;
  const int x = threadIdx.x & 31, y = threadIdx.x >> 5;
#pragma unroll
  for (int i = 0; i < 32; i += 8)
    tile[y + i][x] = src[(size_t)(r0 + y + i) * Cc + c0 + x];
  __syncthreads();
#pragma unroll
  for (int i = 0; i < 32; i += 8)
    dst[(size_t)(c0 + y + i) * R + r0 + x] = f2bf(tile[x][y + i]);
}

__global__ __launch_bounds__(256) void cast_bf16_kernel(
    const float* __restrict__ src, short* __restrict__ dst, int n4)
{
  const int i = blockIdx.x * 256 + threadIdx.x;
  if (i < n4) {
    const float4 v = ((const float4*)src)[i];
    short4 o; o.x = f2bf(v.x); o.y = f2bf(v.y); o.z = f2bf(v.z); o.w = f2bf(v.w);
    ((short4*)dst)[i] = o;
  }
}

__global__ void concat3_kernel(const float* a, const float* b, const float* c, float* o)
{
  const int i = blockIdx.x * 256 + threadIdx.x;
  if (i < 3072) o[i] = (i < 1024 ? a[i] : (i < 2048 ? b[i - 1024] : c[i - 2048]));
}

// ---------------------------------------------------------------------------
extern "C" void kernel_launch(void* const* d_in, const int* in_sizes, int n_in,
                              void* d_out, int out_size, void* d_ws, size_t ws_size,
                              hipStream_t stream)
{
  const float* x    = (const float*)d_in[0];
  const float* Wq   = (const float*)d_in[1];
  const float* bq   = (const float*)d_in[2];
  const float* Wk   = (const float*)d_in[3];
  const float* bk   = (const float*)d_in[4];
  const float* Wv   = (const float*)d_in[5];
  const float* bv   = (const float*)d_in[6];
  const float* Wo   = (const float*)d_in[7];
  const float* bo   = (const float*)d_in[8];
  const float* ln1g = (const float*)d_in[9];
  const float* ln1b = (const float*)d_in[10];
  const float* W1   = (const float*)d_in[11];
  const float* b1   = (const float*)d_in[12];
  const float* W2   = (const float*)d_in[13];
  const float* b2   = (const float*)d_in[14];
  const float* ln2g = (const float*)d_in[15];
  const float* ln2b = (const float*)d_in[16];
  const float* Wc   = (const float*)d_in[17];
  const float* bc   = (const float*)d_in[18];
  float* out = (float*)d_out;

  char* p = (char*)d_ws;
  auto alloc = [&](size_t bytes) { char* r = p; p += (bytes + 255) & ~(size_t)255; return r; };

  short* qkvT = (short*)alloc((size_t)3072 * 1024 * 2);
  short* WoT  = (short*)alloc((size_t)1024 * 1024 * 2);
  short* W1T  = (short*)alloc((size_t)4096 * 1024 * 2);
  short* W2T  = (short*)alloc((size_t)1024 * 4096 * 2);
  short* WcB  = (short*)alloc((size_t)1024 * 1024 * 2);
  float* bqkv = (float*)alloc(3072 * 4);
  // xb/q/k/v are contiguous (all sizes 256-aligned); ff1 (32MB) aliases them.
  short* xb   = (short*)alloc((size_t)4096 * 1024 * 2);
  short* qb_  = (short*)alloc((size_t)32 * 2048 * 64 * 2);
  short* kb_  = (short*)alloc((size_t)32 * 2048 * 64 * 2);
  short* vb_  = (short*)alloc((size_t)32 * 2048 * 64 * 2);
  short* ff1  = xb;
  short* attnO= (short*)alloc((size_t)4096 * 1024 * 2);
  float* h1   = (float*)alloc((size_t)4096 * 1024 * 4);
  short* o1b  = (short*)alloc((size_t)4096 * 1024 * 2);
  float* h2   = (float*)alloc((size_t)4096 * 1024 * 4);
  short* o2b  = (short*)alloc((size_t)4096 * 1024 * 2);

  // weight prep
  cast_bf16_kernel<<<4096, 256, 0, stream>>>(x, xb, 1048576);
  transpose_cast<<<dim3(32, 32),  256, 0, stream>>>(Wq, qkvT,                1024, 1024);
  transpose_cast<<<dim3(32, 32),  256, 0, stream>>>(Wk, qkvT + 1024 * 1024,  1024, 1024);
  transpose_cast<<<dim3(32, 32),  256, 0, stream>>>(Wv, qkvT + 2048 * 1024,  1024, 1024);
  transpose_cast<<<dim3(32, 32),  256, 0, stream>>>(Wo, WoT,                 1024, 1024);
  transpose_cast<<<dim3(128, 32), 256, 0, stream>>>(W1, W1T,                 1024, 4096);
  transpose_cast<<<dim3(32, 128), 256, 0, stream>>>(W2, W2T,                 4096, 1024);
  cast_bf16_kernel<<<1024, 256, 0, stream>>>(Wc, WcB, 262144);
  concat3_kernel<<<12, 256, 0, stream>>>(bq, bk, bv, bqkv);

  // x @ [Wq|Wk|Wv] -> q,k,v (head-major)
  gemm_bt<EPI_QKV><<<dim3(24, 32), 256, 0, stream>>>(
      xb, qkvT, bqkv, nullptr, nullptr, nullptr, qb_, kb_, vb_, 4096, 3072, 1024);
  // attention
  attn_kernel<<<dim3(32, 16), 256, 0, stream>>>(qb_, kb_, vb_, attnO);
  // attn @ Wo + bo + x -> h1
  gemm_bt<EPI_RES><<<dim3(8, 32), 256, 0, stream>>>(
      attnO, WoT, bo, x, h1, nullptr, nullptr, nullptr, nullptr, 4096, 1024, 1024);
  ln_kernel<<<4096, 256, 0, stream>>>(h1, h1, o1b, ln1g, ln1b);
  // gelu(out1 @ W1 + b1) -> ff1 (bf16)
  gemm_bt<EPI_GELU><<<dim3(32, 32), 256, 0, stream>>>(
      o1b, W1T, b1, nullptr, nullptr, ff1, nullptr, nullptr, nullptr, 4096, 4096, 1024);
  // ff1 @ W2 + b2 + out1 -> h2
  gemm_bt<EPI_RES><<<dim3(8, 32), 256, 0, stream>>>(
      ff1, W2T, b2, h1, h2, nullptr, nullptr, nullptr, nullptr, 4096, 1024, 4096);
  ln_kernel<<<4096, 256, 0, stream>>>(h2, h2, o2b, ln2g, ln2b);
  // out2 @ Wc^T + bc -> out (f32)
  gemm_bt<EPI_F32><<<dim3(8, 32), 256, 0, stream>>>(
      o2b, WcB, bc, nullptr, out, nullptr, nullptr, nullptr, nullptr, 4096, 1024, 1024);
}

// Round 4
// 467.744 us; speedup vs baseline: 1.2335x; 1.2335x over previous
//
#include <hip/hip_runtime.h>
#include <hip/hip_bf16.h>
#include <cstdint>
#include <cstddef>

#define DEVINL __device__ __forceinline__

typedef __attribute__((ext_vector_type(4)))  float f32x4;
typedef __attribute__((ext_vector_type(16))) float f32x16;
typedef __attribute__((ext_vector_type(8)))  short s16x8;

#define QSCALE 0.1803368801111204f  // 0.125 * log2(e): softmax runs in exp2 domain

// round-to-nearest-even f32 -> bf16 bits
DEVINL short f2bf(float f) {
  union { float f; unsigned u; } v; v.f = f;
  unsigned r = (v.u + 0x7fffu + ((v.u >> 16) & 1u)) >> 16;
  return (short)r;
}

DEVINL void gload_lds16(const void* g, void* l) {
  __builtin_amdgcn_global_load_lds((const __attribute__((address_space(1))) void*)g,
                                   (__attribute__((address_space(3))) void*)l,
                                   16, 0, 0);
}

// swizzled LDS fragment read: tile rows are 128 B; byte ^= (row&7)<<4
DEVINL s16x8 lds_frag(const short* base, int row, int cb) {
  const int addr = row * 128 + (cb ^ ((row & 7) << 4));
  return *(const s16x8*)((const char*)base + addr);
}

// ---------------------------------------------------------------------------
// GEMM: C(M,N) = A(M,K) @ Bt(N,K)^T, bf16 in, f32 accum, fused epilogues.
// BMx128 tile, BK=32, 4 waves; BM=128 -> wave 64x64 (4x4), BM=64 -> 32x64.
// ---------------------------------------------------------------------------
enum { EPI_F32 = 0, EPI_GELU = 1, EPI_RES = 2, EPI_QKV = 3 };

template <int EPI, int BM>
__global__ __launch_bounds__(256) void gemm_bt(
    const short* __restrict__ A, const short* __restrict__ Bt,
    const float* __restrict__ bias, const float* __restrict__ res,
    float* __restrict__ outF, short* __restrict__ outB,
    short* __restrict__ qp, short* __restrict__ kp, short* __restrict__ vt,
    int M, int N, int K)
{
  constexpr int MI = BM / 32;       // acc rows per wave
  constexpr int CAW = BM / 64;      // A staging chunks per wave
  __shared__ short As[BM * 32];
  __shared__ short Bs[128 * 32];
  const int tid = threadIdx.x;
  const int w = tid >> 6, lane = tid & 63;
  const int wr = w >> 1, wc = w & 1;

  // XCD-aware block swizzle (grid size is a multiple of 8 for every call)
  const int gx = gridDim.x;
  int id = blockIdx.x + gx * blockIdx.y;
  const int cpx = (gx * gridDim.y) >> 3;
  id = (id & 7) * cpx + (id >> 3);
  const int n0 = (id % gx) * 128, m0 = (id / gx) * BM;

  const int lrow = lane >> 2, lk = (lane & 3) << 3;
  const short* Ag = A + (size_t)m0 * K;
  const short* Bg = Bt + (size_t)n0 * K;

  f32x4 acc[MI][4] = {};

  for (int kk = 0; kk < K; kk += 32) {
#pragma unroll
    for (int i = 0; i < CAW; ++i) {
      const int c = w * CAW + i;
      gload_lds16(Ag + (size_t)(c * 16 + lrow) * K + (kk + lk), &As[c * 512]);
    }
#pragma unroll
    for (int i = 0; i < 2; ++i) {
      const int c = w * 2 + i;
      gload_lds16(Bg + (size_t)(c * 16 + lrow) * K + (kk + lk), &Bs[c * 512]);
    }
    __syncthreads();
    s16x8 af[MI], bf[4];
#pragma unroll
    for (int mi = 0; mi < MI; ++mi)
      af[mi] = *(const s16x8*)&As[(wr * (BM / 2) + mi * 16 + (lane & 15)) * 32 + ((lane >> 4) << 3)];
#pragma unroll
    for (int ni = 0; ni < 4; ++ni)
      bf[ni] = *(const s16x8*)&Bs[(wc * 64 + ni * 16 + (lane & 15)) * 32 + ((lane >> 4) << 3)];
#pragma unroll
    for (int mi = 0; mi < MI; ++mi)
#pragma unroll
      for (int ni = 0; ni < 4; ++ni)
        acc[mi][ni] = __builtin_amdgcn_mfma_f32_16x16x32_bf16(af[mi], bf[ni], acc[mi][ni], 0, 0, 0);
    __syncthreads();
  }

  const int rbase = m0 + wr * (BM / 2) + ((lane >> 4) << 2);
  const int cbase = n0 + wc * 64 + (lane & 15);
#pragma unroll
  for (int mi = 0; mi < MI; ++mi) {
#pragma unroll
    for (int ni = 0; ni < 4; ++ni) {
      const int col = cbase + ni * 16;
      const float bv = bias[col];
      if (EPI == EPI_QKV) {
        const int e = col & 1023, id3 = col >> 10;
        const int h = e >> 6, d = e & 63;
        const int row0 = rbase + mi * 16;
        const int b = row0 >> 11, t0 = row0 & 2047;
        if (id3 == 0) {
#pragma unroll
          for (int j = 0; j < 4; ++j)
            qp[((size_t)(b * 16 + h) * 2048 + t0 + j) * 64 + d] = f2bf((acc[mi][ni][j] + bv) * QSCALE);
        } else if (id3 == 1) {
#pragma unroll
          for (int j = 0; j < 4; ++j)
            kp[((size_t)(b * 16 + h) * 2048 + t0 + j) * 64 + d] = f2bf(acc[mi][ni][j] + bv);
        } else {
          short4 pk4;
          pk4.x = f2bf(acc[mi][ni][0] + bv); pk4.y = f2bf(acc[mi][ni][1] + bv);
          pk4.z = f2bf(acc[mi][ni][2] + bv); pk4.w = f2bf(acc[mi][ni][3] + bv);
          *(short4*)&vt[((size_t)(b * 16 + h) * 64 + d) * 2048 + t0] = pk4;
        }
      } else {
#pragma unroll
        for (int j = 0; j < 4; ++j) {
          const int row = rbase + mi * 16 + j;
          float v = acc[mi][ni][j] + bv;
          if (EPI == EPI_GELU) {
            outB[(size_t)row * N + col] = f2bf(0.5f * v * (1.0f + erff(v * 0.70710678118654752f)));
          } else if (EPI == EPI_RES) {
            outF[(size_t)row * N + col] = v + res[(size_t)row * N + col];
          } else {
            outF[(size_t)row * N + col] = v;
          }
        }
      }
    }
  }
}

// ---------------------------------------------------------------------------
// Flash attention, swapped-operand 32x32 MFMA. Grid (32 bh, 16 qb).
// 4 waves x 32 q-rows. S^T = K·Q so P columns are lane-local (lane ql owns
// q=ql); in-register softmax (exp2 domain, q pre-scaled by log2e/8);
// P->A-frag half-exchange via shfl_xor(32)+select (semantics-certain);
// K and V^T staged via global_load_lds with XOR swizzle, double-buffered.
// ---------------------------------------------------------------------------
__global__ __launch_bounds__(256) void attn_kernel(
    const short* __restrict__ qg, const short* __restrict__ kg,
    const short* __restrict__ vtg, short* __restrict__ outB)
{
  __shared__ short Ks[2][64 * 64];
  __shared__ short Vs[2][64 * 64];
  __shared__ float sbuf[4][32];

  const int bh = blockIdx.x, qb = blockIdx.y;
  const int tid = threadIdx.x, w = tid >> 6, lane = tid & 63;
  const int b = bh >> 4, h = bh & 15;
  const int ql = lane & 31, hi = lane >> 5;
  const int qrow = qb * 128 + w * 32 + ql;

  // Q B-frags (held in registers for the whole loop)
  s16x8 qf[4];
  const short* qrp = qg + ((size_t)bh * 2048 + qrow) * 64;
#pragma unroll
  for (int kd = 0; kd < 4; ++kd)
    qf[kd] = *(const s16x8*)(qrp + kd * 16 + hi * 8);

  f32x16 o[2] = {};
  float mrow = -3.0e38f, lsum = 0.f;

  const size_t kbase = (size_t)bh * 2048 * 64;
  const size_t vbase = (size_t)bh * 64 * 2048;

#define STAGE(t, bufi)                                                         \
  {                                                                            \
    _Pragma("unroll") for (int i = 0; i < 2; ++i) {                            \
      const int pb = i * 4096 + w * 1024;                                      \
      const int p = pb + lane * 16;                                            \
      const int row = p >> 7;                                                  \
      const int cs = (p & 127) ^ ((row & 7) << 4);                             \
      gload_lds16(kg + kbase + (size_t)((t) * 64 + row) * 64 + (cs >> 1),      \
                  &Ks[bufi][pb >> 1]);                                         \
      gload_lds16(vtg + vbase + (size_t)row * 2048 + (t) * 64 + (cs >> 1),     \
                  &Vs[bufi][pb >> 1]);                                         \
    }                                                                          \
  }

  STAGE(0, 0);
  __syncthreads();

  for (int t = 0; t < 32; ++t) {
    const int buf = t & 1;
    if (t < 31) STAGE(t + 1, buf ^ 1);
    const short* kb = Ks[buf];
    const short* vb = Vs[buf];

    // S^T = K · Q  (D row = s = crow(r,hi), D col = q = ql)
    f32x16 pS[2] = {};
#pragma unroll
    for (int kd = 0; kd < 4; ++kd) {
      const s16x8 a0 = lds_frag(kb, ql,      kd * 32 + hi * 16);
      const s16x8 a1 = lds_frag(kb, 32 + ql, kd * 32 + hi * 16);
      pS[0] = __builtin_amdgcn_mfma_f32_32x32x16_bf16(a0, qf[kd], pS[0], 0, 0, 0);
      pS[1] = __builtin_amdgcn_mfma_f32_32x32x16_bf16(a1, qf[kd], pS[1], 0, 0, 0);
    }

    // row max for q=ql: 32 in-lane values + partner half (lane^32, same ql)
    float pm = pS[0][0];
#pragma unroll
    for (int r = 1; r < 16; ++r) pm = fmaxf(pm, pS[0][r]);
#pragma unroll
    for (int r = 0; r < 16; ++r) pm = fmaxf(pm, pS[1][r]);
    pm = fmaxf(pm, __shfl_xor(pm, 32));

    if (!__all(pm <= mrow + 8.0f)) {      // defer-max: rescale rarely
      const float mnew = fmaxf(mrow, pm);
      const float alpha = exp2f(mrow - mnew);
      mrow = mnew;
      lsum *= alpha;
      sbuf[w][ql] = alpha;                // broadcast to crow layout
#pragma unroll
      for (int r = 0; r < 16; ++r) {
        const float a = sbuf[w][(r & 3) + 8 * (r >> 2) + 4 * hi];
        o[0][r] *= a; o[1][r] *= a;
      }
    }

    // P = exp2(S - m), row-sum
    float rs = 0.f;
#pragma unroll
    for (int r = 0; r < 16; ++r) { pS[0][r] = exp2f(pS[0][r] - mrow); rs += pS[0][r]; }
#pragma unroll
    for (int r = 0; r < 16; ++r) { pS[1][r] = exp2f(pS[1][r] - mrow); rs += pS[1][r]; }
    rs += __shfl_xor(rs, 32);
    lsum += rs;

    // P -> A-frags. Lane ql holds P[q=ql][s=crow(r,hi)]; A-frag needs
    // P[q=ql][s = ks*16 + hi*8 + j]. Pack pairs, then exchange halves via
    // shfl_xor(32) + select (partner lane has same ql, complementary crow set).
#pragma unroll
    for (int ks = 0; ks < 4; ++ks) {
      const int tI = ks >> 1, b8 = (ks & 1) * 8;
      unsigned u0, u1, v0, v1;
      asm("v_cvt_pk_bf16_f32 %0, %1, %2" : "=v"(u0) : "v"(pS[tI][b8 + 0]), "v"(pS[tI][b8 + 1]));
      asm("v_cvt_pk_bf16_f32 %0, %1, %2" : "=v"(u1) : "v"(pS[tI][b8 + 2]), "v"(pS[tI][b8 + 3]));
      asm("v_cvt_pk_bf16_f32 %0, %1, %2" : "=v"(v0) : "v"(pS[tI][b8 + 4]), "v"(pS[tI][b8 + 5]));
      asm("v_cvt_pk_bf16_f32 %0, %1, %2" : "=v"(v1) : "v"(pS[tI][b8 + 6]), "v"(pS[tI][b8 + 7]));
      const unsigned su0 = (unsigned)__shfl_xor((int)u0, 32);
      const unsigned su1 = (unsigned)__shfl_xor((int)u1, 32);
      const unsigned sv0 = (unsigned)__shfl_xor((int)v0, 32);
      const unsigned sv1 = (unsigned)__shfl_xor((int)v1, 32);
      union { unsigned u[4]; s16x8 s; } pa;
      pa.u[0] = hi ? sv0 : u0;   // j=0,1 : s = ks*16 + hi*8 + {0,1}
      pa.u[1] = hi ? sv1 : u1;   // j=2,3
      pa.u[2] = hi ? v0 : su0;   // j=4,5
      pa.u[3] = hi ? v1 : su1;   // j=6,7
      const s16x8 vf0 = lds_frag(vb, ql,      ks * 32 + hi * 16);
      const s16x8 vf1 = lds_frag(vb, 32 + ql, ks * 32 + hi * 16);
      o[0] = __builtin_amdgcn_mfma_f32_32x32x16_bf16(pa.s, vf0, o[0], 0, 0, 0);
      o[1] = __builtin_amdgcn_mfma_f32_32x32x16_bf16(pa.s, vf1, o[1], 0, 0, 0);
    }
    __syncthreads();
  }

  // normalize + write: lane holds O[q=crow(r,hi)][d=ql and 32+ql]
  sbuf[w][ql] = lsum;
#pragma unroll
  for (int r = 0; r < 16; ++r) {
    const int q = (r & 3) + 8 * (r >> 2) + 4 * hi;
    const float linv = 1.0f / sbuf[w][q];
    const int tq = qb * 128 + w * 32 + q;
    const size_t orow = ((size_t)b * 2048 + tq) * 1024 + h * 64;
    outB[orow + ql]      = f2bf(o[0][r] * linv);
    outB[orow + 32 + ql] = f2bf(o[1][r] * linv);
  }
}

// ---------------------------------------------------------------------------
// LayerNorm over C=1024, one row per block, f32 out + bf16 copy.
// ---------------------------------------------------------------------------
__global__ __launch_bounds__(256) void ln_kernel(
    const float* in, float* outF, short* __restrict__ outB,
    const float* __restrict__ gw, const float* __restrict__ bw)
{
  const int row = blockIdx.x, tid = threadIdx.x;
  const float4 v = ((const float4*)(in + (size_t)row * 1024))[tid];
  float s = v.x + v.y + v.z + v.w;
  float s2 = v.x * v.x + v.y * v.y + v.z * v.z + v.w * v.w;
#pragma unroll
  for (int m = 1; m < 64; m <<= 1) { s += __shfl_xor(s, m); s2 += __shfl_xor(s2, m); }
  __shared__ float as1[4], as2[4];
  if ((tid & 63) == 0) { as1[tid >> 6] = s; as2[tid >> 6] = s2; }
  __syncthreads();
  s = as1[0] + as1[1] + as1[2] + as1[3];
  s2 = as2[0] + as2[1] + as2[2] + as2[3];
  const float mu = s * (1.f / 1024.f);
  const float var = s2 * (1.f / 1024.f) - mu * mu;
  const float rstd = rsqrtf(var + 1e-5f);
  const float4 g = ((const float4*)gw)[tid];
  const float4 bb = ((const float4*)bw)[tid];
  float4 y;
  y.x = (v.x - mu) * rstd * g.x + bb.x;
  y.y = (v.y - mu) * rstd * g.y + bb.y;
  y.z = (v.z - mu) * rstd * g.z + bb.z;
  y.w = (v.w - mu) * rstd * g.w + bb.w;
  ((float4*)(outF + (size_t)row * 1024))[tid] = y;
  short4 ob; ob.x = f2bf(y.x); ob.y = f2bf(y.y); ob.z = f2bf(y.z); ob.w = f2bf(y.w);
  ((short4*)(outB + (size_t)row * 1024))[tid] = ob;
}

// src (R,Cc) f32 -> dst (Cc,R) bf16
__global__ __launch_bounds__(256) void transpose_cast(
    const float* __restrict__ src, short* __restrict__ dst, int R, int Cc)
{
  __shared__ float tile[32][33];
  const int c0 = blockIdx.x * 32, r0 = blockIdx.y * 32;
  const int x = threadIdx.x & 31, y = threadIdx.x >> 5;
#pragma unroll
  for (int i = 0; i < 32; i += 8)
    tile[y + i][x] = src[(size_t)(r0 + y + i) * Cc + c0 + x];
  __syncthreads();
#pragma unroll
  for (int i = 0; i < 32; i += 8)
    dst[(size_t)(c0 + y + i) * R + r0 + x] = f2bf(tile[x][y + i]);
}

__global__ __launch_bounds__(256) void cast_bf16_kernel(
    const float* __restrict__ src, short* __restrict__ dst, int n4)
{
  const int i = blockIdx.x * 256 + threadIdx.x;
  if (i < n4) {
    const float4 v = ((const float4*)src)[i];
    short4 o; o.x = f2bf(v.x); o.y = f2bf(v.y); o.z = f2bf(v.z); o.w = f2bf(v.w);
    ((short4*)dst)[i] = o;
  }
}

__global__ void concat3_kernel(const float* a, const float* b, const float* c, float* o)
{
  const int i = blockIdx.x * 256 + threadIdx.x;
  if (i < 3072) o[i] = (i < 1024 ? a[i] : (i < 2048 ? b[i - 1024] : c[i - 2048]));
}

// ---------------------------------------------------------------------------
extern "C" void kernel_launch(void* const* d_in, const int* in_sizes, int n_in,
                              void* d_out, int out_size, void* d_ws, size_t ws_size,
                              hipStream_t stream)
{
  const float* x    = (const float*)d_in[0];
  const float* Wq   = (const float*)d_in[1];
  const float* bq   = (const float*)d_in[2];
  const float* Wk   = (const float*)d_in[3];
  const float* bk   = (const float*)d_in[4];
  const float* Wv   = (const float*)d_in[5];
  const float* bv   = (const float*)d_in[6];
  const float* Wo   = (const float*)d_in[7];
  const float* bo   = (const float*)d_in[8];
  const float* ln1g = (const float*)d_in[9];
  const float* ln1b = (const float*)d_in[10];
  const float* W1   = (const float*)d_in[11];
  const float* b1   = (const float*)d_in[12];
  const float* W2   = (const float*)d_in[13];
  const float* b2   = (const float*)d_in[14];
  const float* ln2g = (const float*)d_in[15];
  const float* ln2b = (const float*)d_in[16];
  const float* Wc   = (const float*)d_in[17];
  const float* bc   = (const float*)d_in[18];
  float* out = (float*)d_out;

  char* p = (char*)d_ws;
  auto alloc = [&](size_t bytes) { char* r = p; p += (bytes + 255) & ~(size_t)255; return r; };

  short* qkvT = (short*)alloc((size_t)3072 * 1024 * 2);
  short* WoT  = (short*)alloc((size_t)1024 * 1024 * 2);
  short* W1T  = (short*)alloc((size_t)4096 * 1024 * 2);
  short* W2T  = (short*)alloc((size_t)1024 * 4096 * 2);
  short* WcB  = (short*)alloc((size_t)1024 * 1024 * 2);
  float* bqkv = (float*)alloc(3072 * 4);
  short* xb   = (short*)alloc((size_t)4096 * 1024 * 2);
  short* qb_  = (short*)alloc((size_t)32 * 2048 * 64 * 2);
  short* kb_  = (short*)alloc((size_t)32 * 2048 * 64 * 2);
  short* vt_  = (short*)alloc((size_t)32 * 64 * 2048 * 2);   // V^T head-major
  short* ff1  = xb;                                           // aliases xb (xb dead after QKV gemm)
  short* attnO= (short*)alloc((size_t)4096 * 1024 * 2);
  float* h1   = (float*)alloc((size_t)4096 * 1024 * 4);
  short* o1b  = (short*)alloc((size_t)4096 * 1024 * 2);
  float* h2   = (float*)alloc((size_t)4096 * 1024 * 4);
  short* o2b  = (short*)alloc((size_t)4096 * 1024 * 2);

  // weight prep
  cast_bf16_kernel<<<4096, 256, 0, stream>>>(x, xb, 1048576);
  transpose_cast<<<dim3(32, 32),  256, 0, stream>>>(Wq, qkvT,                1024, 1024);
  transpose_cast<<<dim3(32, 32),  256, 0, stream>>>(Wk, qkvT + 1024 * 1024,  1024, 1024);
  transpose_cast<<<dim3(32, 32),  256, 0, stream>>>(Wv, qkvT + 2048 * 1024,  1024, 1024);
  transpose_cast<<<dim3(32, 32),  256, 0, stream>>>(Wo, WoT,                 1024, 1024);
  transpose_cast<<<dim3(128, 32), 256, 0, stream>>>(W1, W1T,                 1024, 4096);
  transpose_cast<<<dim3(32, 128), 256, 0, stream>>>(W2, W2T,                 4096, 1024);
  cast_bf16_kernel<<<1024, 256, 0, stream>>>(Wc, WcB, 262144);
  concat3_kernel<<<12, 256, 0, stream>>>(bq, bk, bv, bqkv);

  // x @ [Wq|Wk|Wv] -> q (pre-scaled), k (head-major), v^T (head-major, transposed)
  gemm_bt<EPI_QKV, 128><<<dim3(24, 32), 256, 0, stream>>>(
      xb, qkvT, bqkv, nullptr, nullptr, nullptr, qb_, kb_, vt_, 4096, 3072, 1024);
  attn_kernel<<<dim3(32, 16), 256, 0, stream>>>(qb_, kb_, vt_, attnO);
  // attn @ Wo + bo + x -> h1
  gemm_bt<EPI_RES, 64><<<dim3(8, 64), 256, 0, stream>>>(
      attnO, WoT, bo, x, h1, nullptr, nullptr, nullptr, nullptr, 4096, 1024, 1024);
  ln_kernel<<<4096, 256, 0, stream>>>(h1, h1, o1b, ln1g, ln1b);
  // gelu(out1 @ W1 + b1) -> ff1 (bf16)
  gemm_bt<EPI_GELU, 128><<<dim3(32, 32), 256, 0, stream>>>(
      o1b, W1T, b1, nullptr, nullptr, ff1, nullptr, nullptr, nullptr, 4096, 4096, 1024);
  // ff1 @ W2 + b2 + out1 -> h2
  gemm_bt<EPI_RES, 64><<<dim3(8, 64), 256, 0, stream>>>(
      ff1, W2T, b2, h1, h2, nullptr, nullptr, nullptr, nullptr, 4096, 1024, 4096);
  ln_kernel<<<4096, 256, 0, stream>>>(h2, h2, o2b, ln2g, ln2b);
  // out2 @ Wc^T + bc -> out (f32)
  gemm_bt<EPI_F32, 64><<<dim3(8, 64), 256, 0, stream>>>(
      o2b, WcB, bc, nullptr, out, nullptr, nullptr, nullptr, nullptr, 4096, 1024, 1024);
}

// Round 5
// 454.558 us; speedup vs baseline: 1.2693x; 1.0290x over previous
//
#include <hip/hip_runtime.h>
#include <hip/hip_bf16.h>
#include <cstdint>
#include <cstddef>

#define DEVINL __device__ __forceinline__

typedef __attribute__((ext_vector_type(4)))  float f32x4;
typedef __attribute__((ext_vector_type(16))) float f32x16;
typedef __attribute__((ext_vector_type(8)))  short s16x8;

#define QSCALE 0.1803368801111204f  // 0.125 * log2(e): softmax runs in exp2 domain

// round-to-nearest-even f32 -> bf16 bits
DEVINL short f2bf(float f) {
  union { float f; unsigned u; } v; v.f = f;
  unsigned r = (v.u + 0x7fffu + ((v.u >> 16) & 1u)) >> 16;
  return (short)r;
}

DEVINL void gload_lds16(const void* g, void* l) {
  __builtin_amdgcn_global_load_lds((const __attribute__((address_space(1))) void*)g,
                                   (__attribute__((address_space(3))) void*)l,
                                   16, 0, 0);
}

// swizzled LDS fragment read: tile rows are 128 B; byte ^= (row&7)<<4
DEVINL s16x8 lds_frag(const short* base, int row, int cb) {
  const int addr = row * 128 + (cb ^ ((row & 7) << 4));
  return *(const s16x8*)((const char*)base + addr);
}

// ---------------------------------------------------------------------------
// GEMM: C(M,N) = A(M,K) @ Bt(N,K)^T, bf16 in, f32 accum, fused epilogues.
// BMx128 tile, BK=32, 4 waves; BM=128 -> wave 64x64 (4x4), BM=64 -> 32x64.
// 2-phase double-buffered: issue next K-tile's global_load_lds BEFORE the
// current tile's ds_read+MFMA; ONE __syncthreads per K-step (its implicit
// vmcnt(0) drain lands after compute, so HBM latency hides under MFMA).
// ---------------------------------------------------------------------------
enum { EPI_F32 = 0, EPI_GELU = 1, EPI_RES = 2, EPI_QKV = 3 };

template <int EPI, int BM>
__global__ __launch_bounds__(256) void gemm_bt(
    const short* __restrict__ A, const short* __restrict__ Bt,
    const float* __restrict__ bias, const float* __restrict__ res,
    float* __restrict__ outF, short* __restrict__ outB,
    short* __restrict__ qp, short* __restrict__ kp, short* __restrict__ vt,
    int M, int N, int K)
{
  constexpr int MI = BM / 32;       // acc rows per wave
  constexpr int CAW = BM / 64;      // A staging chunks per wave
  __shared__ short As[2][BM * 32];
  __shared__ short Bs[2][128 * 32];
  const int tid = threadIdx.x;
  const int w = tid >> 6, lane = tid & 63;
  const int wr = w >> 1, wc = w & 1;

  // XCD-aware block swizzle (grid size is a multiple of 8 for every call)
  const int gx = gridDim.x;
  int id = blockIdx.x + gx * blockIdx.y;
  const int cpx = (gx * gridDim.y) >> 3;
  id = (id & 7) * cpx + (id >> 3);
  const int n0 = (id % gx) * 128, m0 = (id / gx) * BM;

  const int lrow = lane >> 2, lk = (lane & 3) << 3;
  const short* Ag = A + (size_t)m0 * K;
  const short* Bg = Bt + (size_t)n0 * K;

#define GSTAGE(kk, bufi)                                                     \
  {                                                                          \
    _Pragma("unroll") for (int i = 0; i < CAW; ++i) {                        \
      const int c = w * CAW + i;                                             \
      gload_lds16(Ag + (size_t)(c * 16 + lrow) * K + ((kk) + lk),            \
                  &As[bufi][c * 512]);                                       \
    }                                                                        \
    _Pragma("unroll") for (int i = 0; i < 2; ++i) {                          \
      const int c = w * 2 + i;                                               \
      gload_lds16(Bg + (size_t)(c * 16 + lrow) * K + ((kk) + lk),            \
                  &Bs[bufi][c * 512]);                                       \
    }                                                                        \
  }

  f32x4 acc[MI][4] = {};

  GSTAGE(0, 0);
  __syncthreads();
  int cur = 0;

  for (int kk = 0; kk < K; kk += 32) {
    if (kk + 32 < K) GSTAGE(kk + 32, cur ^ 1);   // prefetch next tile
    s16x8 af[MI], bf[4];
#pragma unroll
    for (int mi = 0; mi < MI; ++mi)
      af[mi] = *(const s16x8*)&As[cur][(wr * (BM / 2) + mi * 16 + (lane & 15)) * 32 + ((lane >> 4) << 3)];
#pragma unroll
    for (int ni = 0; ni < 4; ++ni)
      bf[ni] = *(const s16x8*)&Bs[cur][(wc * 64 + ni * 16 + (lane & 15)) * 32 + ((lane >> 4) << 3)];
    __builtin_amdgcn_s_setprio(1);
#pragma unroll
    for (int mi = 0; mi < MI; ++mi)
#pragma unroll
      for (int ni = 0; ni < 4; ++ni)
        acc[mi][ni] = __builtin_amdgcn_mfma_f32_16x16x32_bf16(af[mi], bf[ni], acc[mi][ni], 0, 0, 0);
    __builtin_amdgcn_s_setprio(0);
    __syncthreads();                              // drains prefetch + guards reuse
    cur ^= 1;
  }
#undef GSTAGE

  const int rbase = m0 + wr * (BM / 2) + ((lane >> 4) << 2);
  const int cbase = n0 + wc * 64 + (lane & 15);
#pragma unroll
  for (int mi = 0; mi < MI; ++mi) {
#pragma unroll
    for (int ni = 0; ni < 4; ++ni) {
      const int col = cbase + ni * 16;
      const float bv = bias[col];
      if (EPI == EPI_QKV) {
        const int e = col & 1023, id3 = col >> 10;
        const int h = e >> 6, d = e & 63;
        const int row0 = rbase + mi * 16;
        const int b = row0 >> 11, t0 = row0 & 2047;
        if (id3 == 0) {
#pragma unroll
          for (int j = 0; j < 4; ++j)
            qp[((size_t)(b * 16 + h) * 2048 + t0 + j) * 64 + d] = f2bf((acc[mi][ni][j] + bv) * QSCALE);
        } else if (id3 == 1) {
#pragma unroll
          for (int j = 0; j < 4; ++j)
            kp[((size_t)(b * 16 + h) * 2048 + t0 + j) * 64 + d] = f2bf(acc[mi][ni][j] + bv);
        } else {
          short4 pk4;
          pk4.x = f2bf(acc[mi][ni][0] + bv); pk4.y = f2bf(acc[mi][ni][1] + bv);
          pk4.z = f2bf(acc[mi][ni][2] + bv); pk4.w = f2bf(acc[mi][ni][3] + bv);
          *(short4*)&vt[((size_t)(b * 16 + h) * 64 + d) * 2048 + t0] = pk4;
        }
      } else {
#pragma unroll
        for (int j = 0; j < 4; ++j) {
          const int row = rbase + mi * 16 + j;
          float v = acc[mi][ni][j] + bv;
          if (EPI == EPI_GELU) {
            outB[(size_t)row * N + col] = f2bf(0.5f * v * (1.0f + erff(v * 0.70710678118654752f)));
          } else if (EPI == EPI_RES) {
            outF[(size_t)row * N + col] = v + res[(size_t)row * N + col];
          } else {
            outF[(size_t)row * N + col] = v;
          }
        }
      }
    }
  }
}

// ---------------------------------------------------------------------------
// Flash attention, swapped-operand 32x32 MFMA. Grid (32 bh, 16 qb).
// 4 waves x 32 q-rows. S^T = K·Q so P columns are lane-local (lane ql owns
// q=ql); in-register softmax (exp2 domain, q pre-scaled by log2e/8);
// P->A-frag half-exchange via shfl_xor(32)+select (semantics-certain);
// K and V^T staged via global_load_lds with XOR swizzle, double-buffered.
// ---------------------------------------------------------------------------
__global__ __launch_bounds__(256) void attn_kernel(
    const short* __restrict__ qg, const short* __restrict__ kg,
    const short* __restrict__ vtg, short* __restrict__ outB)
{
  __shared__ short Ks[2][64 * 64];
  __shared__ short Vs[2][64 * 64];
  __shared__ float sbuf[4][32];

  const int bh = blockIdx.x, qb = blockIdx.y;
  const int tid = threadIdx.x, w = tid >> 6, lane = tid & 63;
  const int b = bh >> 4, h = bh & 15;
  const int ql = lane & 31, hi = lane >> 5;
  const int qrow = qb * 128 + w * 32 + ql;

  // Q B-frags (held in registers for the whole loop)
  s16x8 qf[4];
  const short* qrp = qg + ((size_t)bh * 2048 + qrow) * 64;
#pragma unroll
  for (int kd = 0; kd < 4; ++kd)
    qf[kd] = *(const s16x8*)(qrp + kd * 16 + hi * 8);

  f32x16 o[2] = {};
  float mrow = -3.0e38f, lsum = 0.f;

  const size_t kbase = (size_t)bh * 2048 * 64;
  const size_t vbase = (size_t)bh * 64 * 2048;

#define STAGE(t, bufi)                                                         \
  {                                                                            \
    _Pragma("unroll") for (int i = 0; i < 2; ++i) {                            \
      const int pb = i * 4096 + w * 1024;                                      \
      const int p = pb + lane * 16;                                            \
      const int row = p >> 7;                                                  \
      const int cs = (p & 127) ^ ((row & 7) << 4);                             \
      gload_lds16(kg + kbase + (size_t)((t) * 64 + row) * 64 + (cs >> 1),      \
                  &Ks[bufi][pb >> 1]);                                         \
      gload_lds16(vtg + vbase + (size_t)row * 2048 + (t) * 64 + (cs >> 1),     \
                  &Vs[bufi][pb >> 1]);                                         \
    }                                                                          \
  }

  STAGE(0, 0);
  __syncthreads();

  for (int t = 0; t < 32; ++t) {
    const int buf = t & 1;
    if (t < 31) STAGE(t + 1, buf ^ 1);
    const short* kb = Ks[buf];
    const short* vb = Vs[buf];

    // S^T = K · Q  (D row = s = crow(r,hi), D col = q = ql)
    f32x16 pS[2] = {};
    __builtin_amdgcn_s_setprio(1);
#pragma unroll
    for (int kd = 0; kd < 4; ++kd) {
      const s16x8 a0 = lds_frag(kb, ql,      kd * 32 + hi * 16);
      const s16x8 a1 = lds_frag(kb, 32 + ql, kd * 32 + hi * 16);
      pS[0] = __builtin_amdgcn_mfma_f32_32x32x16_bf16(a0, qf[kd], pS[0], 0, 0, 0);
      pS[1] = __builtin_amdgcn_mfma_f32_32x32x16_bf16(a1, qf[kd], pS[1], 0, 0, 0);
    }
    __builtin_amdgcn_s_setprio(0);

    // row max for q=ql: 32 in-lane values + partner half (lane^32, same ql)
    float pm = pS[0][0];
#pragma unroll
    for (int r = 1; r < 16; ++r) pm = fmaxf(pm, pS[0][r]);
#pragma unroll
    for (int r = 0; r < 16; ++r) pm = fmaxf(pm, pS[1][r]);
    pm = fmaxf(pm, __shfl_xor(pm, 32));

    if (!__all(pm <= mrow + 8.0f)) {      // defer-max: rescale rarely
      const float mnew = fmaxf(mrow, pm);
      const float alpha = exp2f(mrow - mnew);
      mrow = mnew;
      lsum *= alpha;
      sbuf[w][ql] = alpha;                // broadcast to crow layout
#pragma unroll
      for (int r = 0; r < 16; ++r) {
        const float a = sbuf[w][(r & 3) + 8 * (r >> 2) + 4 * hi];
        o[0][r] *= a; o[1][r] *= a;
      }
    }

    // P = exp2(S - m), row-sum
    float rs = 0.f;
#pragma unroll
    for (int r = 0; r < 16; ++r) { pS[0][r] = exp2f(pS[0][r] - mrow); rs += pS[0][r]; }
#pragma unroll
    for (int r = 0; r < 16; ++r) { pS[1][r] = exp2f(pS[1][r] - mrow); rs += pS[1][r]; }
    rs += __shfl_xor(rs, 32);
    lsum += rs;

    // P -> A-frags. Lane ql holds P[q=ql][s=crow(r,hi)]; A-frag needs
    // P[q=ql][s = ks*16 + hi*8 + j]. Pack pairs, then exchange halves via
    // shfl_xor(32) + select (partner lane has same ql, complementary crow set).
#pragma unroll
    for (int ks = 0; ks < 4; ++ks) {
      const int tI = ks >> 1, b8 = (ks & 1) * 8;
      unsigned u0, u1, v0, v1;
      asm("v_cvt_pk_bf16_f32 %0, %1, %2" : "=v"(u0) : "v"(pS[tI][b8 + 0]), "v"(pS[tI][b8 + 1]));
      asm("v_cvt_pk_bf16_f32 %0, %1, %2" : "=v"(u1) : "v"(pS[tI][b8 + 2]), "v"(pS[tI][b8 + 3]));
      asm("v_cvt_pk_bf16_f32 %0, %1, %2" : "=v"(v0) : "v"(pS[tI][b8 + 4]), "v"(pS[tI][b8 + 5]));
      asm("v_cvt_pk_bf16_f32 %0, %1, %2" : "=v"(v1) : "v"(pS[tI][b8 + 6]), "v"(pS[tI][b8 + 7]));
      const unsigned su0 = (unsigned)__shfl_xor((int)u0, 32);
      const unsigned su1 = (unsigned)__shfl_xor((int)u1, 32);
      const unsigned sv0 = (unsigned)__shfl_xor((int)v0, 32);
      const unsigned sv1 = (unsigned)__shfl_xor((int)v1, 32);
      union { unsigned u[4]; s16x8 s; } pa;
      pa.u[0] = hi ? sv0 : u0;   // j=0,1 : s = ks*16 + hi*8 + {0,1}
      pa.u[1] = hi ? sv1 : u1;   // j=2,3
      pa.u[2] = hi ? v0 : su0;   // j=4,5
      pa.u[3] = hi ? v1 : su1;   // j=6,7
      const s16x8 vf0 = lds_frag(vb, ql,      ks * 32 + hi * 16);
      const s16x8 vf1 = lds_frag(vb, 32 + ql, ks * 32 + hi * 16);
      __builtin_amdgcn_s_setprio(1);
      o[0] = __builtin_amdgcn_mfma_f32_32x32x16_bf16(pa.s, vf0, o[0], 0, 0, 0);
      o[1] = __builtin_amdgcn_mfma_f32_32x32x16_bf16(pa.s, vf1, o[1], 0, 0, 0);
      __builtin_amdgcn_s_setprio(0);
    }
    __syncthreads();
  }

  // normalize + write: lane holds O[q=crow(r,hi)][d=ql and 32+ql]
  sbuf[w][ql] = lsum;
#pragma unroll
  for (int r = 0; r < 16; ++r) {
    const int q = (r & 3) + 8 * (r >> 2) + 4 * hi;
    const float linv = 1.0f / sbuf[w][q];
    const int tq = qb * 128 + w * 32 + q;
    const size_t orow = ((size_t)b * 2048 + tq) * 1024 + h * 64;
    outB[orow + ql]      = f2bf(o[0][r] * linv);
    outB[orow + 32 + ql] = f2bf(o[1][r] * linv);
  }
}

// ---------------------------------------------------------------------------
// LayerNorm over C=1024, one row per block, f32 out + bf16 copy.
// ---------------------------------------------------------------------------
__global__ __launch_bounds__(256) void ln_kernel(
    const float* in, float* outF, short* __restrict__ outB,
    const float* __restrict__ gw, const float* __restrict__ bw)
{
  const int row = blockIdx.x, tid = threadIdx.x;
  const float4 v = ((const float4*)(in + (size_t)row * 1024))[tid];
  float s = v.x + v.y + v.z + v.w;
  float s2 = v.x * v.x + v.y * v.y + v.z * v.z + v.w * v.w;
#pragma unroll
  for (int m = 1; m < 64; m <<= 1) { s += __shfl_xor(s, m); s2 += __shfl_xor(s2, m); }
  __shared__ float as1[4], as2[4];
  if ((tid & 63) == 0) { as1[tid >> 6] = s; as2[tid >> 6] = s2; }
  __syncthreads();
  s = as1[0] + as1[1] + as1[2] + as1[3];
  s2 = as2[0] + as2[1] + as2[2] + as2[3];
  const float mu = s * (1.f / 1024.f);
  const float var = s2 * (1.f / 1024.f) - mu * mu;
  const float rstd = rsqrtf(var + 1e-5f);
  const float4 g = ((const float4*)gw)[tid];
  const float4 bb = ((const float4*)bw)[tid];
  float4 y;
  y.x = (v.x - mu) * rstd * g.x + bb.x;
  y.y = (v.y - mu) * rstd * g.y + bb.y;
  y.z = (v.z - mu) * rstd * g.z + bb.z;
  y.w = (v.w - mu) * rstd * g.w + bb.w;
  ((float4*)(outF + (size_t)row * 1024))[tid] = y;
  short4 ob; ob.x = f2bf(y.x); ob.y = f2bf(y.y); ob.z = f2bf(y.z); ob.w = f2bf(y.w);
  ((short4*)(outB + (size_t)row * 1024))[tid] = ob;
}

// src (R,Cc) f32 -> dst (Cc,R) bf16
__global__ __launch_bounds__(256) void transpose_cast(
    const float* __restrict__ src, short* __restrict__ dst, int R, int Cc)
{
  __shared__ float tile[32][33];
  const int c0 = blockIdx.x * 32, r0 = blockIdx.y * 32;
  const int x = threadIdx.x & 31, y = threadIdx.x >> 5;
#pragma unroll
  for (int i = 0; i < 32; i += 8)
    tile[y + i][x] = src[(size_t)(r0 + y + i) * Cc + c0 + x];
  __syncthreads();
#pragma unroll
  for (int i = 0; i < 32; i += 8)
    dst[(size_t)(c0 + y + i) * R + r0 + x] = f2bf(tile[x][y + i]);
}

__global__ __launch_bounds__(256) void cast_bf16_kernel(
    const float* __restrict__ src, short* __restrict__ dst, int n4)
{
  const int i = blockIdx.x * 256 + threadIdx.x;
  if (i < n4) {
    const float4 v = ((const float4*)src)[i];
    short4 o; o.x = f2bf(v.x); o.y = f2bf(v.y); o.z = f2bf(v.z); o.w = f2bf(v.w);
    ((short4*)dst)[i] = o;
  }
}

__global__ void concat3_kernel(const float* a, const float* b, const float* c, float* o)
{
  const int i = blockIdx.x * 256 + threadIdx.x;
  if (i < 3072) o[i] = (i < 1024 ? a[i] : (i < 2048 ? b[i - 1024] : c[i - 2048]));
}

// ---------------------------------------------------------------------------
extern "C" void kernel_launch(void* const* d_in, const int* in_sizes, int n_in,
                              void* d_out, int out_size, void* d_ws, size_t ws_size,
                              hipStream_t stream)
{
  const float* x    = (const float*)d_in[0];
  const float* Wq   = (const float*)d_in[1];
  const float* bq   = (const float*)d_in[2];
  const float* Wk   = (const float*)d_in[3];
  const float* bk   = (const float*)d_in[4];
  const float* Wv   = (const float*)d_in[5];
  const float* bv   = (const float*)d_in[6];
  const float* Wo   = (const float*)d_in[7];
  const float* bo   = (const float*)d_in[8];
  const float* ln1g = (const float*)d_in[9];
  const float* ln1b = (const float*)d_in[10];
  const float* W1   = (const float*)d_in[11];
  const float* b1   = (const float*)d_in[12];
  const float* W2   = (const float*)d_in[13];
  const float* b2   = (const float*)d_in[14];
  const float* ln2g = (const float*)d_in[15];
  const float* ln2b = (const float*)d_in[16];
  const float* Wc   = (const float*)d_in[17];
  const float* bc   = (const float*)d_in[18];
  float* out = (float*)d_out;

  char* p = (char*)d_ws;
  auto alloc = [&](size_t bytes) { char* r = p; p += (bytes + 255) & ~(size_t)255; return r; };

  short* qkvT = (short*)alloc((size_t)3072 * 1024 * 2);
  short* WoT  = (short*)alloc((size_t)1024 * 1024 * 2);
  short* W1T  = (short*)alloc((size_t)4096 * 1024 * 2);
  short* W2T  = (short*)alloc((size_t)1024 * 4096 * 2);
  short* WcB  = (short*)alloc((size_t)1024 * 1024 * 2);
  float* bqkv = (float*)alloc(3072 * 4);
  short* xb   = (short*)alloc((size_t)4096 * 1024 * 2);
  short* qb_  = (short*)alloc((size_t)32 * 2048 * 64 * 2);
  short* kb_  = (short*)alloc((size_t)32 * 2048 * 64 * 2);
  short* vt_  = (short*)alloc((size_t)32 * 64 * 2048 * 2);   // V^T head-major
  short* ff1  = xb;                                           // aliases xb (xb dead after QKV gemm)
  short* attnO= (short*)alloc((size_t)4096 * 1024 * 2);
  float* h1   = (float*)alloc((size_t)4096 * 1024 * 4);
  short* o1b  = (short*)alloc((size_t)4096 * 1024 * 2);
  float* h2   = (float*)alloc((size_t)4096 * 1024 * 4);
  short* o2b  = (short*)alloc((size_t)4096 * 1024 * 2);

  // weight prep
  cast_bf16_kernel<<<4096, 256, 0, stream>>>(x, xb, 1048576);
  transpose_cast<<<dim3(32, 32),  256, 0, stream>>>(Wq, qkvT,                1024, 1024);
  transpose_cast<<<dim3(32, 32),  256, 0, stream>>>(Wk, qkvT + 1024 * 1024,  1024, 1024);
  transpose_cast<<<dim3(32, 32),  256, 0, stream>>>(Wv, qkvT + 2048 * 1024,  1024, 1024);
  transpose_cast<<<dim3(32, 32),  256, 0, stream>>>(Wo, WoT,                 1024, 1024);
  transpose_cast<<<dim3(128, 32), 256, 0, stream>>>(W1, W1T,                 1024, 4096);
  transpose_cast<<<dim3(32, 128), 256, 0, stream>>>(W2, W2T,                 4096, 1024);
  cast_bf16_kernel<<<1024, 256, 0, stream>>>(Wc, WcB, 262144);
  concat3_kernel<<<12, 256, 0, stream>>>(bq, bk, bv, bqkv);

  // x @ [Wq|Wk|Wv] -> q (pre-scaled), k (head-major), v^T (head-major, transposed)
  gemm_bt<EPI_QKV, 128><<<dim3(24, 32), 256, 0, stream>>>(
      xb, qkvT, bqkv, nullptr, nullptr, nullptr, qb_, kb_, vt_, 4096, 3072, 1024);
  attn_kernel<<<dim3(32, 16), 256, 0, stream>>>(qb_, kb_, vt_, attnO);
  // attn @ Wo + bo + x -> h1
  gemm_bt<EPI_RES, 64><<<dim3(8, 64), 256, 0, stream>>>(
      attnO, WoT, bo, x, h1, nullptr, nullptr, nullptr, nullptr, 4096, 1024, 1024);
  ln_kernel<<<4096, 256, 0, stream>>>(h1, h1, o1b, ln1g, ln1b);
  // gelu(out1 @ W1 + b1) -> ff1 (bf16)
  gemm_bt<EPI_GELU, 128><<<dim3(32, 32), 256, 0, stream>>>(
      o1b, W1T, b1, nullptr, nullptr, ff1, nullptr, nullptr, nullptr, 4096, 4096, 1024);
  // ff1 @ W2 + b2 + out1 -> h2
  gemm_bt<EPI_RES, 64><<<dim3(8, 64), 256, 0, stream>>>(
      ff1, W2T, b2, h1, h2, nullptr, nullptr, nullptr, nullptr, 4096, 1024, 4096);
  ln_kernel<<<4096, 256, 0, stream>>>(h2, h2, o2b, ln2g, ln2b);
  // out2 @ Wc^T + bc -> out (f32)
  gemm_bt<EPI_F32, 64><<<dim3(8, 64), 256, 0, stream>>>(
      o2b, WcB, bc, nullptr, out, nullptr, nullptr, nullptr, nullptr, 4096, 1024, 1024);
}

// Round 9
// 443.941 us; speedup vs baseline: 1.2997x; 1.0239x over previous
//
#include <hip/hip_runtime.h>
#include <hip/hip_bf16.h>
#include <cstdint>
#include <cstddef>

#define DEVINL __device__ __forceinline__

typedef __attribute__((ext_vector_type(4)))  float f32x4;
typedef __attribute__((ext_vector_type(16))) float f32x16;
typedef __attribute__((ext_vector_type(8)))  short s16x8;

#define QSCALE 0.1803368801111204f  // 0.125 * log2(e): softmax runs in exp2 domain

// round-to-nearest-even f32 -> bf16 bits
DEVINL short f2bf(float f) {
  union { float f; unsigned u; } v; v.f = f;
  unsigned r = (v.u + 0x7fffu + ((v.u >> 16) & 1u)) >> 16;
  return (short)r;
}
DEVINL float bf2f(short s) {
  union { unsigned u; float f; } v; v.u = ((unsigned)(unsigned short)s) << 16;
  return v.f;
}

DEVINL void gload_lds16(const void* g, void* l) {
  __builtin_amdgcn_global_load_lds((const __attribute__((address_space(1))) void*)g,
                                   (__attribute__((address_space(3))) void*)l,
                                   16, 0, 0);
}

// swizzled LDS fragment read: tile rows are 128 B; byte ^= (row&7)<<4
DEVINL s16x8 lds_frag(const short* base, int row, int cb) {
  const int addr = row * 128 + (cb ^ ((row & 7) << 4));
  return *(const s16x8*)((const char*)base + addr);
}

// ---------------------------------------------------------------------------
// GEMM: C(M,N) = A(M,K) @ Bt(N,K)^T, bf16 in, f32 accum, fused epilogues.
// BMx128 tile, BK=32, 4 waves; 2-phase double-buffered prefetch + setprio.
// ---------------------------------------------------------------------------
enum { EPI_F32 = 0, EPI_GELU = 1, EPI_RES = 2, EPI_QKV = 3 };

template <int EPI, int BM>
__global__ __launch_bounds__(256) void gemm_bt(
    const short* __restrict__ A, const short* __restrict__ Bt,
    const float* __restrict__ bias, const float* __restrict__ res,
    float* __restrict__ outF, short* __restrict__ outB,
    short* __restrict__ qp, short* __restrict__ kp, short* __restrict__ vt,
    int M, int N, int K)
{
  constexpr int MI = BM / 32;       // acc rows per wave
  constexpr int CAW = BM / 64;      // A staging chunks per wave
  __shared__ short As[2][BM * 32];
  __shared__ short Bs[2][128 * 32];
  const int tid = threadIdx.x;
  const int w = tid >> 6, lane = tid & 63;
  const int wr = w >> 1, wc = w & 1;

  // XCD-aware block swizzle (grid size is a multiple of 8 for every call)
  const int gx = gridDim.x;
  int id = blockIdx.x + gx * blockIdx.y;
  const int cpx = (gx * gridDim.y) >> 3;
  id = (id & 7) * cpx + (id >> 3);
  const int n0 = (id % gx) * 128, m0 = (id / gx) * BM;

  const int lrow = lane >> 2, lk = (lane & 3) << 3;
  const short* Ag = A + (size_t)m0 * K;
  const short* Bg = Bt + (size_t)n0 * K;

#define GSTAGE(kk, bufi)                                                     \
  {                                                                          \
    _Pragma("unroll") for (int i = 0; i < CAW; ++i) {                        \
      const int c = w * CAW + i;                                             \
      gload_lds16(Ag + (size_t)(c * 16 + lrow) * K + ((kk) + lk),            \
                  &As[bufi][c * 512]);                                       \
    }                                                                        \
    _Pragma("unroll") for (int i = 0; i < 2; ++i) {                          \
      const int c = w * 2 + i;                                               \
      gload_lds16(Bg + (size_t)(c * 16 + lrow) * K + ((kk) + lk),            \
                  &Bs[bufi][c * 512]);                                       \
    }                                                                        \
  }

  f32x4 acc[MI][4] = {};

  GSTAGE(0, 0);
  __syncthreads();
  int cur = 0;

  for (int kk = 0; kk < K; kk += 32) {
    if (kk + 32 < K) GSTAGE(kk + 32, cur ^ 1);   // prefetch next tile
    s16x8 af[MI], bf[4];
#pragma unroll
    for (int mi = 0; mi < MI; ++mi)
      af[mi] = *(const s16x8*)&As[cur][(wr * (BM / 2) + mi * 16 + (lane & 15)) * 32 + ((lane >> 4) << 3)];
#pragma unroll
    for (int ni = 0; ni < 4; ++ni)
      bf[ni] = *(const s16x8*)&Bs[cur][(wc * 64 + ni * 16 + (lane & 15)) * 32 + ((lane >> 4) << 3)];
    __builtin_amdgcn_s_setprio(1);
#pragma unroll
    for (int mi = 0; mi < MI; ++mi)
#pragma unroll
      for (int ni = 0; ni < 4; ++ni)
        acc[mi][ni] = __builtin_amdgcn_mfma_f32_16x16x32_bf16(af[mi], bf[ni], acc[mi][ni], 0, 0, 0);
    __builtin_amdgcn_s_setprio(0);
    __syncthreads();                              // drains prefetch + guards reuse
    cur ^= 1;
  }
#undef GSTAGE

  const int rbase = m0 + wr * (BM / 2) + ((lane >> 4) << 2);
  const int cbase = n0 + wc * 64 + (lane & 15);
#pragma unroll
  for (int mi = 0; mi < MI; ++mi) {
#pragma unroll
    for (int ni = 0; ni < 4; ++ni) {
      const int col = cbase + ni * 16;
      const float bv = bias[col];
      if (EPI == EPI_QKV) {
        const int e = col & 1023, id3 = col >> 10;
        const int h = e >> 6, d = e & 63;
        const int row0 = rbase + mi * 16;
        const int b = row0 >> 11, t0 = row0 & 2047;
        if (id3 == 0) {
#pragma unroll
          for (int j = 0; j < 4; ++j)
            qp[((size_t)(b * 16 + h) * 2048 + t0 + j) * 64 + d] = f2bf((acc[mi][ni][j] + bv) * QSCALE);
        } else if (id3 == 1) {
#pragma unroll
          for (int j = 0; j < 4; ++j)
            kp[((size_t)(b * 16 + h) * 2048 + t0 + j) * 64 + d] = f2bf(acc[mi][ni][j] + bv);
        } else {
          short4 pk4;
          pk4.x = f2bf(acc[mi][ni][0] + bv); pk4.y = f2bf(acc[mi][ni][1] + bv);
          pk4.z = f2bf(acc[mi][ni][2] + bv); pk4.w = f2bf(acc[mi][ni][3] + bv);
          *(short4*)&vt[((size_t)(b * 16 + h) * 64 + d) * 2048 + t0] = pk4;
        }
      } else {
#pragma unroll
        for (int j = 0; j < 4; ++j) {
          const int row = rbase + mi * 16 + j;
          float v = acc[mi][ni][j] + bv;
          if (EPI == EPI_GELU) {
            outB[(size_t)row * N + col] = f2bf(0.5f * v * (1.0f + erff(v * 0.70710678118654752f)));
          } else if (EPI == EPI_RES) {
            outF[(size_t)row * N + col] = v + res[(size_t)row * N + col];
          } else {
            outF[(size_t)row * N + col] = v;
          }
        }
      }
    }
  }
}

// ---------------------------------------------------------------------------
// Flash attention, swapped-operand 32x32 MFMA, KV-SPLIT x2.
// Grid (32 bh, 16 qb, 2 ks). Each block handles 1024 keys (16 tiles of 64);
// writes normalized partial O (bf16) and L = m + log2(l) (f32).
// ---------------------------------------------------------------------------
__global__ __launch_bounds__(256) void attn_kernel(
    const short* __restrict__ qg, const short* __restrict__ kg,
    const short* __restrict__ vtg, short* __restrict__ part,
    float* __restrict__ Lst)
{
  __shared__ short Ks[2][64 * 64];
  __shared__ short Vs[2][64 * 64];
  __shared__ float sbuf[4][32];

  const int bh = blockIdx.x, qb = blockIdx.y, ks2 = blockIdx.z;
  const int tid = threadIdx.x, w = tid >> 6, lane = tid & 63;
  const int b = bh >> 4, h = bh & 15;
  const int ql = lane & 31, hi = lane >> 5;
  const int qrow = qb * 128 + w * 32 + ql;

  // Q B-frags (held in registers for the whole loop)
  s16x8 qf[4];
  const short* qrp = qg + ((size_t)bh * 2048 + qrow) * 64;
#pragma unroll
  for (int kd = 0; kd < 4; ++kd)
    qf[kd] = *(const s16x8*)(qrp + kd * 16 + hi * 8);

  f32x16 o[2] = {};
  float mrow = -3.0e38f, lsum = 0.f;

  const size_t kbase = (size_t)bh * 2048 * 64 + (size_t)ks2 * 1024 * 64;
  const size_t vbase = (size_t)bh * 64 * 2048;
  const int scol0 = ks2 * 1024;

#define STAGE(t, bufi)                                                         \
  {                                                                            \
    _Pragma("unroll") for (int i = 0; i < 2; ++i) {                            \
      const int pb = i * 4096 + w * 1024;                                      \
      const int p = pb + lane * 16;                                            \
      const int row = p >> 7;                                                  \
      const int cs = (p & 127) ^ ((row & 7) << 4);                             \
      gload_lds16(kg + kbase + (size_t)((t) * 64 + row) * 64 + (cs >> 1),      \
                  &Ks[bufi][pb >> 1]);                                         \
      gload_lds16(vtg + vbase + (size_t)row * 2048 + scol0 + (t) * 64 + (cs >> 1), \
                  &Vs[bufi][pb >> 1]);                                         \
    }                                                                          \
  }

  STAGE(0, 0);
  __syncthreads();

  for (int t = 0; t < 16; ++t) {
    const int buf = t & 1;
    if (t < 15) STAGE(t + 1, buf ^ 1);
    const short* kb = Ks[buf];
    const short* vb = Vs[buf];

    // S^T = K · Q  (D row = s = crow(r,hi), D col = q = ql)
    f32x16 pS[2] = {};
    __builtin_amdgcn_s_setprio(1);
#pragma unroll
    for (int kd = 0; kd < 4; ++kd) {
      const s16x8 a0 = lds_frag(kb, ql,      kd * 32 + hi * 16);
      const s16x8 a1 = lds_frag(kb, 32 + ql, kd * 32 + hi * 16);
      pS[0] = __builtin_amdgcn_mfma_f32_32x32x16_bf16(a0, qf[kd], pS[0], 0, 0, 0);
      pS[1] = __builtin_amdgcn_mfma_f32_32x32x16_bf16(a1, qf[kd], pS[1], 0, 0, 0);
    }
    __builtin_amdgcn_s_setprio(0);

    // row max for q=ql: 32 in-lane values + partner half (lane^32, same ql)
    float pm = pS[0][0];
#pragma unroll
    for (int r = 1; r < 16; ++r) pm = fmaxf(pm, pS[0][r]);
#pragma unroll
    for (int r = 0; r < 16; ++r) pm = fmaxf(pm, pS[1][r]);
    pm = fmaxf(pm, __shfl_xor(pm, 32));

    if (!__all(pm <= mrow + 8.0f)) {      // defer-max: rescale rarely
      const float mnew = fmaxf(mrow, pm);
      const float alpha = exp2f(mrow - mnew);
      mrow = mnew;
      lsum *= alpha;
      sbuf[w][ql] = alpha;                // broadcast to crow layout
#pragma unroll
      for (int r = 0; r < 16; ++r) {
        const float a = sbuf[w][(r & 3) + 8 * (r >> 2) + 4 * hi];
        o[0][r] *= a; o[1][r] *= a;
      }
    }

    // P = exp2(S - m), row-sum
    float rs = 0.f;
#pragma unroll
    for (int r = 0; r < 16; ++r) { pS[0][r] = exp2f(pS[0][r] - mrow); rs += pS[0][r]; }
#pragma unroll
    for (int r = 0; r < 16; ++r) { pS[1][r] = exp2f(pS[1][r] - mrow); rs += pS[1][r]; }
    rs += __shfl_xor(rs, 32);
    lsum += rs;

    // P -> A-frags: pack pairs, exchange halves via shfl_xor(32) + select
#pragma unroll
    for (int ks = 0; ks < 4; ++ks) {
      const int tI = ks >> 1, b8 = (ks & 1) * 8;
      unsigned u0, u1, v0, v1;
      asm("v_cvt_pk_bf16_f32 %0, %1, %2" : "=v"(u0) : "v"(pS[tI][b8 + 0]), "v"(pS[tI][b8 + 1]));
      asm("v_cvt_pk_bf16_f32 %0, %1, %2" : "=v"(u1) : "v"(pS[tI][b8 + 2]), "v"(pS[tI][b8 + 3]));
      asm("v_cvt_pk_bf16_f32 %0, %1, %2" : "=v"(v0) : "v"(pS[tI][b8 + 4]), "v"(pS[tI][b8 + 5]));
      asm("v_cvt_pk_bf16_f32 %0, %1, %2" : "=v"(v1) : "v"(pS[tI][b8 + 6]), "v"(pS[tI][b8 + 7]));
      const unsigned su0 = (unsigned)__shfl_xor((int)u0, 32);
      const unsigned su1 = (unsigned)__shfl_xor((int)u1, 32);
      const unsigned sv0 = (unsigned)__shfl_xor((int)v0, 32);
      const unsigned sv1 = (unsigned)__shfl_xor((int)v1, 32);
      union { unsigned u[4]; s16x8 s; } pa;
      pa.u[0] = hi ? sv0 : u0;   // j=0,1 : s = ks*16 + hi*8 + {0,1}
      pa.u[1] = hi ? sv1 : u1;   // j=2,3
      pa.u[2] = hi ? v0 : su0;   // j=4,5
      pa.u[3] = hi ? v1 : su1;   // j=6,7
      const s16x8 vf0 = lds_frag(vb, ql,      ks * 32 + hi * 16);
      const s16x8 vf1 = lds_frag(vb, 32 + ql, ks * 32 + hi * 16);
      __builtin_amdgcn_s_setprio(1);
      o[0] = __builtin_amdgcn_mfma_f32_32x32x16_bf16(pa.s, vf0, o[0], 0, 0, 0);
      o[1] = __builtin_amdgcn_mfma_f32_32x32x16_bf16(pa.s, vf1, o[1], 0, 0, 0);
      __builtin_amdgcn_s_setprio(0);
    }
    __syncthreads();
  }

  // normalized partial write + L stat
  short* po = part + (size_t)ks2 * (4096 * 1024);
  sbuf[w][ql] = lsum;
  if (hi == 0)
    Lst[ks2 * 65536 + bh * 2048 + qb * 128 + w * 32 + ql] = mrow + log2f(lsum);
#pragma unroll
  for (int r = 0; r < 16; ++r) {
    const int q = (r & 3) + 8 * (r >> 2) + 4 * hi;
    const float linv = 1.0f / sbuf[w][q];
    const int tq = qb * 128 + w * 32 + q;
    const size_t orow = ((size_t)b * 2048 + tq) * 1024 + h * 64;
    po[orow + ql]      = f2bf(o[0][r] * linv);
    po[orow + 32 + ql] = f2bf(o[1][r] * linv);
  }
}

// combine the two KV-split partials: out = (w0*p0 + w1*p1)/(w0+w1)
__global__ __launch_bounds__(256) void attn_combine(
    const short* __restrict__ part, const float* __restrict__ Lst,
    short* __restrict__ outB)
{
  const int gid = blockIdx.x * 256 + threadIdx.x;  // 524288 total
  const int row = gid >> 7;                        // b*2048 + t
  const int wi = gid & 127;
  const int h = wi >> 3, d8 = (wi & 7) * 8;
  const int b = row >> 11, t = row & 2047;
  const int bh = b * 16 + h;
  const float L0 = Lst[bh * 2048 + t];
  const float L1 = Lst[65536 + bh * 2048 + t];
  const float mx = fmaxf(L0, L1);
  const float w0 = exp2f(L0 - mx), w1 = exp2f(L1 - mx);
  const float inv = 1.f / (w0 + w1);
  const float a0 = w0 * inv, a1 = w1 * inv;
  const size_t off = (size_t)row * 1024 + h * 64 + d8;
  const s16x8 p0 = *(const s16x8*)&part[off];
  const s16x8 p1 = *(const s16x8*)&part[(size_t)4096 * 1024 + off];
  s16x8 ov;
#pragma unroll
  for (int e = 0; e < 8; ++e)
    ov[e] = f2bf(a0 * bf2f(p0[e]) + a1 * bf2f(p1[e]));
  *(s16x8*)&outB[off] = ov;
}

// ---------------------------------------------------------------------------
// LayerNorm over C=1024, one row per block, f32 out + bf16 copy.
// ---------------------------------------------------------------------------
__global__ __launch_bounds__(256) void ln_kernel(
    const float* in, float* outF, short* __restrict__ outB,
    const float* __restrict__ gw, const float* __restrict__ bw)
{
  const int row = blockIdx.x, tid = threadIdx.x;
  const float4 v = ((const float4*)(in + (size_t)row * 1024))[tid];
  float s = v.x + v.y + v.z + v.w;
  float s2 = v.x * v.x + v.y * v.y + v.z * v.z + v.w * v.w;
#pragma unroll
  for (int m = 1; m < 64; m <<= 1) { s += __shfl_xor(s, m); s2 += __shfl_xor(s2, m); }
  __shared__ float as1[4], as2[4];
  if ((tid & 63) == 0) { as1[tid >> 6] = s; as2[tid >> 6] = s2; }
  __syncthreads();
  s = as1[0] + as1[1] + as1[2] + as1[3];
  s2 = as2[0] + as2[1] + as2[2] + as2[3];
  const float mu = s * (1.f / 1024.f);
  const float var = s2 * (1.f / 1024.f) - mu * mu;
  const float rstd = rsqrtf(var + 1e-5f);
  const float4 g = ((const float4*)gw)[tid];
  const float4 bb = ((const float4*)bw)[tid];
  float4 y;
  y.x = (v.x - mu) * rstd * g.x + bb.x;
  y.y = (v.y - mu) * rstd * g.y + bb.y;
  y.z = (v.z - mu) * rstd * g.z + bb.z;
  y.w = (v.w - mu) * rstd * g.w + bb.w;
  ((float4*)(outF + (size_t)row * 1024))[tid] = y;
  short4 ob; ob.x = f2bf(y.x); ob.y = f2bf(y.y); ob.z = f2bf(y.z); ob.w = f2bf(y.w);
  ((short4*)(outB + (size_t)row * 1024))[tid] = ob;
}

// ---------------------------------------------------------------------------
// Merged prep: x cast, 6 weight transposes, Wc cast, bias concat. One launch.
// ---------------------------------------------------------------------------
__global__ __launch_bounds__(256) void prep_kernel(
    const float* __restrict__ x,  const float* __restrict__ Wq,
    const float* __restrict__ Wk, const float* __restrict__ Wv,
    const float* __restrict__ Wo, const float* __restrict__ W1,
    const float* __restrict__ W2, const float* __restrict__ Wc,
    const float* __restrict__ bq, const float* __restrict__ bk,
    const float* __restrict__ bv,
    short* __restrict__ xb, short* __restrict__ qkvT, short* __restrict__ WoT,
    short* __restrict__ W1T, short* __restrict__ W2T, short* __restrict__ WcB,
    float* __restrict__ bqkv)
{
  __shared__ float tile[32][33];
  const int bid = blockIdx.x, tid = threadIdx.x;
  const float* tsrc = nullptr; short* tdst = nullptr;
  const float* csrc = nullptr; short* cdst = nullptr;
  int R = 0, Cc = 0, tb = 0, cb = 0;
  if (bid < 4096)        { csrc = x;  cdst = xb;  cb = bid; }
  else if (bid < 5120)   { tsrc = Wq; tdst = qkvT;           R = 1024; Cc = 1024; tb = bid - 4096; }
  else if (bid < 6144)   { tsrc = Wk; tdst = qkvT + 1048576; R = 1024; Cc = 1024; tb = bid - 5120; }
  else if (bid < 7168)   { tsrc = Wv; tdst = qkvT + 2097152; R = 1024; Cc = 1024; tb = bid - 6144; }
  else if (bid < 8192)   { tsrc = Wo; tdst = WoT;            R = 1024; Cc = 1024; tb = bid - 7168; }
  else if (bid < 12288)  { tsrc = W1; tdst = W1T;            R = 1024; Cc = 4096; tb = bid - 8192; }
  else if (bid < 16384)  { tsrc = W2; tdst = W2T;            R = 4096; Cc = 1024; tb = bid - 12288; }
  else if (bid < 17408)  { csrc = Wc; cdst = WcB; cb = bid - 16384; }
  else {
    const int i = (bid - 17408) * 256 + tid;
    if (i < 3072) bqkv[i] = (i < 1024 ? bq[i] : (i < 2048 ? bk[i - 1024] : bv[i - 2048]));
    return;
  }
  if (csrc) {
    const int i = cb * 256 + tid;
    const float4 v = ((const float4*)csrc)[i];
    short4 oq; oq.x = f2bf(v.x); oq.y = f2bf(v.y); oq.z = f2bf(v.z); oq.w = f2bf(v.w);
    ((short4*)cdst)[i] = oq;
    return;
  }
  const int xtiles = Cc >> 5;
  const int bx = tb % xtiles, by = tb / xtiles;
  const int c0 = bx * 32, r0 = by * 32;
  const int xx = tid & 31, yy = tid >> 5;
#pragma unroll
  for (int i = 0; i < 32; i += 8)
    tile[yy + i][xx] = tsrc[(size_t)(r0 + yy + i) * Cc + c0 + xx];
  __syncthreads();
#pragma unroll
  for (int i = 0; i < 32; i += 8)
    tdst[(size_t)(c0 + yy + i) * R + r0 + xx] = f2bf(tile[xx][yy + i]);
}

// ---------------------------------------------------------------------------
extern "C" void kernel_launch(void* const* d_in, const int* in_sizes, int n_in,
                              void* d_out, int out_size, void* d_ws, size_t ws_size,
                              hipStream_t stream)
{
  const float* x    = (const float*)d_in[0];
  const float* Wq   = (const float*)d_in[1];
  const float* bq   = (const float*)d_in[2];
  const float* Wk   = (const float*)d_in[3];
  const float* bk   = (const float*)d_in[4];
  const float* Wv   = (const float*)d_in[5];
  const float* bv   = (const float*)d_in[6];
  const float* Wo   = (const float*)d_in[7];
  const float* bo   = (const float*)d_in[8];
  const float* ln1g = (const float*)d_in[9];
  const float* ln1b = (const float*)d_in[10];
  const float* W1   = (const float*)d_in[11];
  const float* b1   = (const float*)d_in[12];
  const float* W2   = (const float*)d_in[13];
  const float* b2   = (const float*)d_in[14];
  const float* ln2g = (const float*)d_in[15];
  const float* ln2b = (const float*)d_in[16];
  const float* Wc   = (const float*)d_in[17];
  const float* bc   = (const float*)d_in[18];
  float* out = (float*)d_out;

  char* p = (char*)d_ws;
  auto alloc = [&](size_t bytes) { char* r = p; p += (bytes + 255) & ~(size_t)255; return r; };

  short* qkvT = (short*)alloc((size_t)3072 * 1024 * 2);
  short* WoT  = (short*)alloc((size_t)1024 * 1024 * 2);
  short* W1T  = (short*)alloc((size_t)4096 * 1024 * 2);
  short* W2T  = (short*)alloc((size_t)1024 * 4096 * 2);
  short* WcB  = (short*)alloc((size_t)1024 * 1024 * 2);
  float* bqkv = (float*)alloc(3072 * 4);
  short* xb   = (short*)alloc((size_t)4096 * 1024 * 2);
  short* qb_  = (short*)alloc((size_t)32 * 2048 * 64 * 2);
  short* kb_  = (short*)alloc((size_t)32 * 2048 * 64 * 2);
  short* vt_  = (short*)alloc((size_t)32 * 64 * 2048 * 2);   // V^T head-major
  short* ff1  = xb;                                           // aliases xb (dead after QKV gemm)
  short* attnO= (short*)alloc((size_t)4096 * 1024 * 2);
  float* h1   = (float*)alloc((size_t)4096 * 1024 * 4);
  short* o1b  = (short*)alloc((size_t)4096 * 1024 * 2);
  float* h2   = (float*)alloc((size_t)4096 * 1024 * 4);
  short* o2b  = (short*)alloc((size_t)4096 * 1024 * 2);

  // attn partials alias h1 (16MB: 2 x 8MB bf16); L stats alias h2 (512KB).
  // Both are fully dead until the Wo-GEMM / FF2-GEMM write them later.
  short* part = (short*)h1;
  float* Lst  = (float*)h2;

  prep_kernel<<<17420, 256, 0, stream>>>(x, Wq, Wk, Wv, Wo, W1, W2, Wc,
                                         bq, bk, bv,
                                         xb, qkvT, WoT, W1T, W2T, WcB, bqkv);

  // x @ [Wq|Wk|Wv] -> q (pre-scaled), k (head-major), v^T (head-major, transposed)
  gemm_bt<EPI_QKV, 128><<<dim3(24, 32), 256, 0, stream>>>(
      xb, qkvT, bqkv, nullptr, nullptr, nullptr, qb_, kb_, vt_, 4096, 3072, 1024);
  attn_kernel<<<dim3(32, 16, 2), 256, 0, stream>>>(qb_, kb_, vt_, part, Lst);
  attn_combine<<<2048, 256, 0, stream>>>(part, Lst, attnO);
  // attn @ Wo + bo + x -> h1
  gemm_bt<EPI_RES, 64><<<dim3(8, 64), 256, 0, stream>>>(
      attnO, WoT, bo, x, h1, nullptr, nullptr, nullptr, nullptr, 4096, 1024, 1024);
  ln_kernel<<<4096, 256, 0, stream>>>(h1, h1, o1b, ln1g, ln1b);
  // gelu(out1 @ W1 + b1) -> ff1 (bf16)
  gemm_bt<EPI_GELU, 128><<<dim3(32, 32), 256, 0, stream>>>(
      o1b, W1T, b1, nullptr, nullptr, ff1, nullptr, nullptr, nullptr, 4096, 4096, 1024);
  // ff1 @ W2 + b2 + out1 -> h2
  gemm_bt<EPI_RES, 64><<<dim3(8, 64), 256, 0, stream>>>(
      ff1, W2T, b2, h1, h2, nullptr, nullptr, nullptr, nullptr, 4096, 1024, 4096);
  ln_kernel<<<4096, 256, 0, stream>>>(h2, h2, o2b, ln2g, ln2b);
  // out2 @ Wc^T + bc -> out (f32)
  gemm_bt<EPI_F32, 64><<<dim3(8, 64), 256, 0, stream>>>(
      o2b, WcB, bc, nullptr, out, nullptr, nullptr, nullptr, nullptr, 4096, 1024, 1024);
}